// Round 12
// baseline (101.988 us; speedup 1.0000x reference)
//
#include <hip/hip_runtime.h>
#include <math.h>

typedef float f32x4 __attribute__((ext_vector_type(4)));
typedef __attribute__((address_space(3))) unsigned int lds_u32;
typedef __attribute__((address_space(1))) const unsigned int glb_u32;

// ---------------------------------------------------------------------------
// R32: ROLLED tile loop (#pragma unroll 1) on the proven R24 schedule.
//
// Theory: pass1 is pinned at ~37us (back-solved vs R7's direct split) across
// SEVEN structures -- occupancy 2/4/6 blk/CU, 2/8/16 barriers, counted-vmcnt
// pipeline, half-work triangular -- all flat, issue floor ~15us, all pulled
// counters low. The one invariant: every variant fully unrolled the tile
// loop into ~5-6K instructions (~40-50KB text) > 32KB L1I. Frontend
// starvation is invisible to every counter pulled so far and inflates wall
// time uniformly, insensitive to scheduling/occupancy/work -- matching all
// observations. R32 rolls the 8-tile loop into one ~300-700-instr body
// (total text ~8-10KB, fits L1I); inner pi/pj/r/ks loops stay unrolled
// (register arrays need static indices, rule #20). Everything else is the
// measured-equal R24/R31 hybrid: double-buffered global_load_lds staging,
// one __syncthreads per phase, LDS-staged labels, register A-fragments,
// exp2 scale-folding (rows scaled by sqrt(log2e/T), epilogue raw exp2f,
// sacc *= ln2 at flush).
// ---------------------------------------------------------------------------

// Kernel 1: row normalization -> fp8 e4m3 rows PRE-SWIZZLED (16B chunk c of
// row r stored at chunk c ^ (r&7)). Zeroes out[0].
__global__ __launch_bounds__(256) void norm_kernel(
    const float* __restrict__ X, unsigned char* __restrict__ Y8,
    float* __restrict__ out, float scaleAB) {
  int t = threadIdx.x;
  int row = blockIdx.x * 8 + (t >> 5);
  int l32 = t & 31;
  float4 v = ((const float4*)(X + (size_t)row * 128))[l32];
  float s = v.x * v.x + v.y * v.y + v.z * v.z + v.w * v.w;
  s += __shfl_xor(s, 1);
  s += __shfl_xor(s, 2);
  s += __shfl_xor(s, 4);
  s += __shfl_xor(s, 8);
  s += __shfl_xor(s, 16);
  float inv = scaleAB * rsqrtf(fmaxf(s, 1e-24f));
  int pk = __builtin_amdgcn_cvt_pk_fp8_f32(v.x * inv, v.y * inv, 0, false);
  pk = __builtin_amdgcn_cvt_pk_fp8_f32(v.z * inv, v.w * inv, pk, true);
  int chunk = l32 >> 2;
  int off = ((chunk ^ (row & 7)) << 4) + ((l32 & 3) << 2);
  *(unsigned int*)(Y8 + (size_t)row * 128 + off) = (unsigned)pk;
  if (blockIdx.x == 0 && t == 0) out[0] = 0.f;
}

// ---------------------------------------------------------------------------
// Kernel 2: similarity pass, 64 panels x 16 chunks = 1024 blocks x 256 thr.
// Block (bi,c): rows [bi*128,+128) x cols [c*512,+512) in 8 tiles of 64
// cols; double-buffered LDS staging, ONE rolled loop (the R32 change).
__global__ __launch_bounds__(256, 4) void pass1_kernel(
    const unsigned char* __restrict__ Y8, const int* __restrict__ lab,
    float* __restrict__ P, float* __restrict__ Q, float* __restrict__ S,
    int N) {
  __shared__ unsigned char Bs[2][64][128];  // 16.4KB double buffer
  __shared__ int labC[512];
  __shared__ float sS[4];

  const int b = blockIdx.x;
  const int bi = b >> 4, c = b & 15;
  const int i0 = bi * 128;
  const int j0 = c * 512;
  const int t = threadIdx.x;
  const int w = t >> 6, lane = t & 63;
  const int quad = lane >> 4, l16 = lane & 15;
  const int rbase = w * 32;  // wave owns rows [rbase, rbase+32)
  const int sw = l16 & 7;

  // ---- prologue: stage tile 0, labels, A-fragments (drained once) ----
#pragma unroll
  for (int k = 0; k < 2; ++k) {
    const int c0 = w * 64 + k * 256;  // wave-uniform 16B-chunk index
    const int cc = c0 + lane;
    __builtin_amdgcn_global_load_lds(
        (glb_u32*)(Y8 + (size_t)j0 * 128 + (size_t)cc * 16),
        (lds_u32*)((unsigned char*)&Bs[0][0][0] + c0 * 16), 16, 0, 0);
  }
  labC[t] = lab[j0 + t];
  labC[t + 256] = lab[j0 + 256 + t];

  long af[4][2];  // A fragments: one-time swizzled gathers (L2/L3-hot)
#pragma unroll
  for (int ks = 0; ks < 4; ++ks) {
    const int ch = ks * 2 + (quad >> 1);
    const int off = ((ch ^ sw) << 4) + ((quad & 1) << 3);
#pragma unroll
    for (int p = 0; p < 2; ++p)
      af[ks][p] =
          *(const long*)(Y8 + (size_t)(i0 + rbase + p * 16 + l16) * 128 + off);
  }
  int lr[2][4];
#pragma unroll
  for (int pi = 0; pi < 2; ++pi)
#pragma unroll
    for (int r = 0; r < 4; ++r)
      lr[pi][r] = lab[i0 + rbase + pi * 16 + quad * 4 + r];

  float trow[2][4] = {};  // row exp-sums (self excluded on diag phase)
  float pr[2][4] = {};    // row positive exp-sums
  float sacc = 0.f;       // sum of s*log2e over positives (non-self)

  __syncthreads();  // tile 0 + labC staged; vmcnt drained

  // ==== THE R32 CHANGE: rolled tile loop (text fits L1I) ====
#pragma unroll 1
  for (int jt = 0; jt < 8; ++jt) {
    const int cur = jt & 1;
    const int jt0 = j0 + jt * 64;

    if (jt < 7) {  // stage next tile into the other buffer
      const unsigned char* src = Y8 + (size_t)(jt0 + 64) * 128;
      unsigned char* dst = (unsigned char*)&Bs[cur ^ 1][0][0];
#pragma unroll
      for (int k = 0; k < 2; ++k) {
        const int c0 = w * 64 + k * 256;
        const int cc = c0 + lane;
        __builtin_amdgcn_global_load_lds((glb_u32*)(src + (size_t)cc * 16),
                                         (lds_u32*)(dst + c0 * 16), 16, 0, 0);
      }
    }

    int lc[4];
#pragma unroll
    for (int pj = 0; pj < 4; ++pj) lc[pj] = labC[jt * 64 + pj * 16 + l16];

    f32x4 acc[2][4] = {};
#pragma unroll
    for (int ks = 0; ks < 4; ++ks) {
      const int ch = ks * 2 + (quad >> 1);
      const int off = ((ch ^ sw) << 4) + ((quad & 1) << 3);
      long bf[4];
#pragma unroll
      for (int p = 0; p < 4; ++p)
        bf[p] = *(const long*)&Bs[cur][p * 16 + l16][off];
#pragma unroll
      for (int pi = 0; pi < 2; ++pi)
#pragma unroll
        for (int pj = 0; pj < 4; ++pj)
          acc[pi][pj] = __builtin_amdgcn_mfma_f32_16x16x32_fp8_fp8(
              af[ks][pi], bf[pj], acc[pi][pj], 0, 0, 0);
    }

    // branch-free epilogue; e = exp2(s*log2e)
    const bool dphase = ((jt0 >> 7) == bi);  // wave-uniform
    if (dphase) {
#pragma unroll
      for (int pi = 0; pi < 2; ++pi)
#pragma unroll
        for (int pj = 0; pj < 4; ++pj)
#pragma unroll
          for (int r = 0; r < 4; ++r) {
            const float s2 = acc[pi][pj][r];
            const float e = exp2f(s2);
            const int rowl = rbase + pi * 16 + quad * 4 + r;
            const bool self = (i0 + rowl) == (jt0 + pj * 16 + l16);
            const bool match = (lr[pi][r] == lc[pj]) && !self;
            trow[pi][r] += self ? 0.f : e;
            pr[pi][r] += match ? e : 0.f;
            sacc += match ? s2 : 0.f;
          }
    } else {
#pragma unroll
      for (int pi = 0; pi < 2; ++pi)
#pragma unroll
        for (int pj = 0; pj < 4; ++pj)
#pragma unroll
          for (int r = 0; r < 4; ++r) {
            const float s2 = acc[pi][pj][r];
            const float e = exp2f(s2);
            const bool match = (lr[pi][r] == lc[pj]);
            trow[pi][r] += e;
            pr[pi][r] += match ? e : 0.f;
            sacc += match ? s2 : 0.f;
          }
    }
    __syncthreads();  // buffer handoff + drains next-tile staging
  }

  // ---- flush: reduce across the 16 col-lanes, write-once partials ----
#pragma unroll
  for (int pi = 0; pi < 2; ++pi)
#pragma unroll
    for (int r = 0; r < 4; ++r) {
      float v = trow[pi][r], q = pr[pi][r];
      v += __shfl_xor(v, 1);
      q += __shfl_xor(q, 1);
      v += __shfl_xor(v, 2);
      q += __shfl_xor(q, 2);
      v += __shfl_xor(v, 4);
      q += __shfl_xor(q, 4);
      v += __shfl_xor(v, 8);
      q += __shfl_xor(q, 8);
      if (l16 == 0) {
        const int row = rbase + pi * 16 + quad * 4 + r;
        P[c * N + i0 + row] = v;  // (u + p) partial for this chunk
        Q[c * N + i0 + row] = q;  // p partial
      }
    }
#pragma unroll
  for (int m = 1; m < 64; m <<= 1) sacc += __shfl_xor(sacc, m);
  if (lane == 0) sS[w] = sacc;
  __syncthreads();
  if (t == 0)
    S[b] = (sS[0] + sS[1] + sS[2] + sS[3]) * 0.69314718056f;  // * ln2
}

// ---------------------------------------------------------------------------
// Kernel 3: parallel finalize — 32 blocks x 256 thr, 256 rows each.
// LDS label histogram, fold 16 chunk-partials per row, subtract this
// block's S-slice (32 of 1024), one device atomic per block into out[0].
__global__ __launch_bounds__(256) void finalize_kernel(
    const int* __restrict__ lab, const float* __restrict__ P,
    const float* __restrict__ Q, const float* __restrict__ S,
    float* __restrict__ out, int N) {
  __shared__ int hist[256];
  __shared__ float red[4];
  const int b = blockIdx.x, t = threadIdx.x;
  const int lane = t & 63, w = t >> 6;
  hist[t] = 0;
  __syncthreads();
  for (int i = t; i < N; i += 256) atomicAdd(&hist[lab[i] & 255], 1);
  __syncthreads();

  const int i = b * 256 + t;
  float tot = 0.f, p = 0.f;
#pragma unroll
  for (int cc = 0; cc < 16; ++cc) {
    tot += P[cc * N + i];
    p += Q[cc * N + i];
  }
  const float u = tot - p;
  const float cnti = (float)(hist[lab[i] & 255] - 1);
  float local = cnti * __logf(u) + p / u;
  if (t < 32) local -= S[b * 32 + t];  // fold this block's S-slice
#pragma unroll
  for (int m = 1; m < 64; m <<= 1) local += __shfl_xor(local, m);
  if (lane == 0) red[w] = local;
  __syncthreads();
  if (t == 0) {
    float np = 0.f;
    for (int k = 0; k < 256; ++k) {
      const float m = (float)hist[k];
      np += m * m;
    }
    atomicAdd(out, (red[0] + red[1] + red[2] + red[3]) / (np - (float)N));
  }
}

// ---------------------------------------------------------------------------
extern "C" void kernel_launch(void* const* d_in, const int* in_sizes, int n_in,
                              void* d_out, int out_size, void* d_ws,
                              size_t ws_size, hipStream_t stream) {
  const float* X = (const float*)d_in[0];
  const int* lab = (const int*)d_in[1];
  float* out = (float*)d_out;

  const int N = in_sizes[1];  // 8192; D fixed at 128

  // workspace: Y8 (1MB) | P[16][N] (512KB) | Q[16][N] (512KB) | S[1024]
  unsigned char* Y8 = (unsigned char*)d_ws;
  float* P = (float*)(Y8 + (size_t)N * 128);
  float* Q = P + 16 * (size_t)N;
  float* S = Q + 16 * (size_t)N;

  // sqrt(log2e / T): MFMA outputs s*log2e so the epilogue is raw exp2
  const float scaleAB = 2.68579102f;  // sqrt(1.44269504 / 0.2)

  norm_kernel<<<N / 8, 256, 0, stream>>>(X, Y8, out, scaleAB);

  const int nblk = (N / 128) * 16;  // 64 panels x 16 chunks = 1024
  pass1_kernel<<<nblk, 256, 0, stream>>>(Y8, lab, P, Q, S, N);
  finalize_kernel<<<32, 256, 0, stream>>>(lab, P, Q, S, out, N);
}